// Round 6
// baseline (303.082 us; speedup 1.0000x reference)
//
#include <hip/hip_runtime.h>

// Trilinear 3D-LUT apply: lut [1,3,33,33,33] f32, x [8,3,1024,1024] f32 in [0,1)
// out [8,3,1024,1024] f32.
//
// V5: OCCUPANCY DOUBLING. LDS cube stored as fp16 SINGLES (35937*2 = 71,874 B)
//     -> 2 blocks/CU (was 1 at 143.7 KB) -> 32 resident waves/CU.
//     Diagnosis: V1..V4 all latency-bound (~100us with VALU floor 29us, HBM
//     floor ~35us, LDS ~14us; occupancy capped at 16 waves by LDS size).
//     V4 proved source-level SW pipelining is compiler-defeated (VGPR stayed
//     52). TLP is the remaining lever; fp16 is what makes the cube fit twice.
//     Gather structure = V1's 8 independent reads (fastest variant so far),
//     as ds_read_u16; corner pairs packed and lerped via v_dot2_f32_f16.
//     Side benefit: the 2 co-resident blocks/CU are (chunk,c) and (chunk,c+1)
//     -> identical x reads, L1/L2 sharing.

#define D   33
#define D2  (33 * 33)
#define D3  (33 * 33 * 33)      // 35937 fp16 = 71,874 B LDS
#define HW  (1024 * 1024)
#define QHW (HW / 4)            // float4 groups per plane = 2^18
#define CHUNKS 256
#define GPC ((8 * QHW) / CHUNKS) // groups per chunk = 8192
#define THREADS 1024
#define ITERS (GPC / THREADS)    // 8

typedef __fp16 h16;
typedef __attribute__((ext_vector_type(2))) __fp16 h16x2;

#define DOT2(a, b) __builtin_amdgcn_fdot2((a), (b), 0.0f, false)

// 2nd launch_bounds arg = min waves/EU: 8 waves/EU * 4 EU / 16 waves-per-block
// = 2 blocks/CU target; caps VGPR at 64 (current usage ~52, fits).
__global__ __launch_bounds__(THREADS, 8) void lut3d_kernel(
    const float* __restrict__ lut, const float* __restrict__ x,
    float* __restrict__ out)
{
    const int c     = blockIdx.x;   // channel fastest: co-resident blocks share x
    const int chunk = blockIdx.y;

    // --- stage one channel cube as fp16 singles -----------------------------
    __shared__ h16 ls[D3];
    {
        const float* lc = lut + c * D3;
        for (int i = threadIdx.x; i < D3; i += THREADS) ls[i] = (h16)lc[i];
    }
    __syncthreads();

    const unsigned short* lu = (const unsigned short*)ls;

    const int tid  = threadIdx.x;
    const int base = chunk * GPC;            // chunk never straddles a batch plane
    const int bidx = base >> 18;             // batch index, block-constant
    const int pb   = (base & (QHW - 1)) * 4; // float offset of chunk in plane

    const float* xp = x   + (size_t)bidx * 3 * HW + pb;
    float*       op = out + (size_t)bidx * 3 * HW + (size_t)c * HW + pb;

    #pragma unroll 1
    for (int it = 0; it < ITERS; ++it) {
        const int fo = it * (THREADS * 4) + tid * 4;

        const float4 xr = *(const float4*)(xp + fo);
        const float4 xg = *(const float4*)(xp + fo + HW);
        const float4 xB = *(const float4*)(xp + fo + 2 * HW);

        const float rr[4] = {xr.x, xr.y, xr.z, xr.w};
        const float gg[4] = {xg.x, xg.y, xg.z, xg.w};
        const float bb[4] = {xB.x, xB.y, xB.z, xB.w};
        float oo[4];

        #pragma unroll
        for (int j = 0; j < 4; ++j) {
            // clamp(x,0,1)*32 capped below 32: i0<=31 always -> neighbor
            // offsets +1/+33/+1089 are compile-time constants.
            const float vr = fminf(fmaxf(rr[j], 0.f) * 32.f, 31.999998f);
            const float vg = fminf(fmaxf(gg[j], 0.f) * 32.f, 31.999998f);
            const float vb = fminf(fmaxf(bb[j], 0.f) * 32.f, 31.999998f);

            const int r0 = (int)vr, g0 = (int)vg, b0 = (int)vb;  // trunc==floor
            const float fb = vb - (float)b0;
            const float fg = vg - (float)g0;
            const float fr = vr - (float)r0;

            const int idx = __mul24(r0, D2) + __mul24(g0, D) + b0;

            // pack b-weights once; each corner: 2x ds_read_u16 -> pack -> dot2
            const h16x2 w = __builtin_amdgcn_cvt_pkrtz(1.0f - fb, fb);

            auto cpair = [&](int i) -> float {
                const unsigned int p = (unsigned int)lu[i]
                                     | ((unsigned int)lu[i + 1] << 16);
                return DOT2(__builtin_bit_cast(h16x2, p), w);
            };

            const float c00 = cpair(idx);
            const float c01 = cpair(idx + D);
            const float c10 = cpair(idx + D2);
            const float c11 = cpair(idx + D2 + D);

            const float cg0 = c00 + fg * (c01 - c00);
            const float cg1 = c10 + fg * (c11 - c10);
            oo[j] = cg0 + fr * (cg1 - cg0);
        }

        *(float4*)(op + fo) = make_float4(oo[0], oo[1], oo[2], oo[3]);
    }
}

extern "C" void kernel_launch(void* const* d_in, const int* in_sizes, int n_in,
                              void* d_out, int out_size, void* d_ws, size_t ws_size,
                              hipStream_t stream) {
    const float* lut = (const float*)d_in[0];   // [1,3,33,33,33]
    const float* x   = (const float*)d_in[1];   // [8,3,1024,1024]
    float* out = (float*)d_out;                 // [8,3,1024,1024]

    dim3 grid(3, CHUNKS);
    lut3d_kernel<<<grid, THREADS, 0, stream>>>(lut, x, out);
}

// Round 7
// 199.215 us; speedup vs baseline: 1.5214x; 1.5214x over previous
//
#include <hip/hip_runtime.h>

// Trilinear 3D-LUT apply: lut [1,3,33,33,33] f32, x [8,3,1024,1024] f32 in [0,1)
// out [8,3,1024,1024] f32.
//
// V6: revert to the PROVEN V1 structure (f32 LDS cube, 8 f32 gathers/pixel,
//     1024-thread blocks, 1 block/CU, grid (3,CHUNKS)) and attack the real
//     bottleneck: exposed global-load latency. Enforce a 2-iteration-deep
//     prefetch pipeline with __builtin_amdgcn_sched_barrier(0) so the compiler
//     CANNOT sink the prefetch loads to their use (V4 failure mode: VGPR stayed
//     52 -> loads sunk). LDS (143.7 KB) caps residency at 16 waves/CU, so VGPR
//     up to ~128 is free: 6 float4 loads in flight/lane ~= 98 KB/CU >> ~9.2 KB
//     Little's-law requirement for full HBM rate.
//     Also: clamp-to-31.999998 (validated V3b/V5) -> constant neighbor offsets
//     -> compiler merges gather pairs into 4x ds_read2_b32.
//
// Success criterion: VGPR_Count ~80-104 (pipeline materialized). Predicted
// dispatch 90 -> 55-68 us, hbm 2.9 -> ~4.5-5 TB/s.

#define D   33
#define D2  (33 * 33)
#define D3  (33 * 33 * 33)      // 35937 floats = 143,748 B LDS -> 1 block/CU
#define HW  (1024 * 1024)
#define QHW (HW / 4)            // float4 groups per plane = 2^18
#define CHUNKS 256
#define GPC ((8 * QHW) / CHUNKS) // groups per chunk = 8192
#define THREADS 1024
#define ITERS (GPC / THREADS)    // 8 float4-groups per thread

__global__ __launch_bounds__(THREADS) void lut3d_kernel(
    const float* __restrict__ lut, const float* __restrict__ x,
    float* __restrict__ out)
{
    const int c     = blockIdx.x;   // channel fastest: chunk-triple adjacent -> L2 x-sharing
    const int chunk = blockIdx.y;

    // --- stage one channel cube in f32 --------------------------------------
    __shared__ float ls[D3];
    {
        const float* lc = lut + c * D3;
        for (int i = threadIdx.x; i < D3; i += THREADS) ls[i] = lc[i];
    }
    __syncthreads();

    const int tid  = threadIdx.x;
    const int base = chunk * GPC;            // chunk never straddles a batch plane
    const int bidx = base >> 18;             // batch index, block-constant
    const int pb   = (base & (QHW - 1)) * 4; // float offset of chunk in plane

    const float* xp = x   + (size_t)bidx * 3 * HW + pb;
    float*       op = out + (size_t)bidx * 3 * HW + (size_t)c * HW + pb;

    // load the 3 channel float4s of group `it`
    auto LD = [&](int it, float4& r, float4& g, float4& b) {
        const int fo = it * (THREADS * 4) + tid * 4;
        r = *(const float4*)(xp + fo);
        g = *(const float4*)(xp + fo + HW);
        b = *(const float4*)(xp + fo + 2 * HW);
    };

    // compute + store one float4-group (4 pixels)
    auto DO = [&](int it, const float4& xr, const float4& xg, const float4& xB) {
        const float rr[4] = {xr.x, xr.y, xr.z, xr.w};
        const float gg[4] = {xg.x, xg.y, xg.z, xg.w};
        const float bb[4] = {xB.x, xB.y, xB.z, xB.w};
        float oo[4];
        #pragma unroll
        for (int j = 0; j < 4; ++j) {
            // clamp(x,0,1)*32 capped below 32: i0<=31 always -> +1/+33/+1089
            // neighbor offsets are compile-time constants; gather pairs merge
            // into ds_read2_b32 (offsets {0,1},{33,34} from idx and idx+1089).
            const float vr = fminf(fmaxf(rr[j], 0.f) * 32.f, 31.999998f);
            const float vg = fminf(fmaxf(gg[j], 0.f) * 32.f, 31.999998f);
            const float vb = fminf(fmaxf(bb[j], 0.f) * 32.f, 31.999998f);

            const int r0 = (int)vr, g0 = (int)vg, b0 = (int)vb;  // trunc==floor
            const float fr = vr - (float)r0;
            const float fg = vg - (float)g0;
            const float fb = vb - (float)b0;

            const int idx = __mul24(r0, D2) + __mul24(g0, D) + b0;

            const float c000 = ls[idx];
            const float c001 = ls[idx + 1];
            const float c010 = ls[idx + D];
            const float c011 = ls[idx + D + 1];
            const float c100 = ls[idx + D2];
            const float c101 = ls[idx + D2 + 1];
            const float c110 = ls[idx + D2 + D];
            const float c111 = ls[idx + D2 + D + 1];

            const float c00 = c000 + fb * (c001 - c000);
            const float c01 = c010 + fb * (c011 - c010);
            const float c10 = c100 + fb * (c101 - c100);
            const float c11 = c110 + fb * (c111 - c110);
            const float c0  = c00 + fg * (c01 - c00);
            const float c1  = c10 + fg * (c11 - c10);
            oo[j] = c0 + fr * (c1 - c0);
        }
        const int fo = it * (THREADS * 4) + tid * 4;
        *(float4*)(op + fo) = make_float4(oo[0], oo[1], oo[2], oo[3]);
    };

    // --- enforced 2-deep software pipeline ----------------------------------
    float4 ar, ag, ab_, br, bg, bb_;
    LD(0, ar, ag, ab_);
    LD(1, br, bg, bb_);

    #pragma unroll 1
    for (int it = 0; it < ITERS - 2; it += 2) {
        float4 nr, ng, nb_, mr, mg, mb_;
        LD(it + 2, nr, ng, nb_);             // issue next pair's 6 loads FIRST
        LD(it + 3, mr, mg, mb_);
        __builtin_amdgcn_sched_barrier(0);   // fence: loads may not sink below
        DO(it,     ar, ag, ab_);             // compute current pair (covers latency)
        DO(it + 1, br, bg, bb_);
        ar = nr; ag = ng; ab_ = nb_;
        br = mr; bg = mg; bb_ = mb_;
    }
    DO(ITERS - 2, ar, ag, ab_);              // drain
    DO(ITERS - 1, br, bg, bb_);
}

extern "C" void kernel_launch(void* const* d_in, const int* in_sizes, int n_in,
                              void* d_out, int out_size, void* d_ws, size_t ws_size,
                              hipStream_t stream) {
    const float* lut = (const float*)d_in[0];   // [1,3,33,33,33]
    const float* x   = (const float*)d_in[1];   // [8,3,1024,1024]
    float* out = (float*)d_out;                 // [8,3,1024,1024]

    dim3 grid(3, CHUNKS);
    lut3d_kernel<<<grid, THREADS, 0, stream>>>(lut, x, out);
}